// Round 1
// 175.282 us; speedup vs baseline: 1.0956x; 1.0956x over previous
//
#include <hip/hip_runtime.h>
#include <math.h>

// z = (64,64,64,64) fp32 -> 262144 vectors of dim 64; codebook = 1024 x 64 fp32.
constexpr int DIM  = 64;
constexpr int KCB  = 1024;
constexpr int NVEC = 262144;
constexpr long long NELEM = 16777216LL;
constexpr int WAVES   = 16;              // 1024 threads/block
constexpr int ROWS_PB = 1024;            // 64 rows per wave
constexpr int GRID    = NVEC / ROWS_PB;  // 256 blocks = exactly 1 per CU

typedef short bf16x8 __attribute__((ext_vector_type(8)));  // 8 bf16 = 4 VGPRs
typedef float f32x4  __attribute__((ext_vector_type(4)));

// fp32 -> bf16 round-to-nearest-even, result in low 16 bits
__device__ __forceinline__ unsigned f2bfu(float f) {
    union { float f; unsigned u; } v; v.f = f;
    return (v.u + 0x7fffu + ((v.u >> 16) & 1u)) >> 16;
}

// Single fused kernel. Whole codebook staged once in LDS (128 KB bf16(-2*cb),
// XOR-swizzled: 16-B unit `part` of codeword `col` at slot col*8+((part+col)&7)
// so ds_read_b128 fragments are <=2-way bank-conflict (free, m136)), esq in
// LDS, then a barrier-free 64-iteration MFMA/min loop. Loss comes from the
// tracked min distance itself (||z-e||^2 = ||z||^2 + (||e||^2 - 2<e,z>)), so
// the old z re-read epilogue is gone entirely.
__global__ __launch_bounds__(1024, 4) void vq_fused(
        const float* __restrict__ z,
        const float* __restrict__ cb,
        float* __restrict__ out,
        float* __restrict__ ws) {

    __shared__ unsigned sB[KCB * 32];       // 128 KB swizzled bf16(-2*cb)
    __shared__ float    s_esq[KCB];         // 4 KB ||e_k||^2
    __shared__ int      s_idx[WAVES * 64];  // 4 KB per-wave argmin exchange

    const int tid  = threadIdx.x;
    const int lane = tid & 63;
    const int wave = tid >> 6;
    const int quad = lane >> 4;
    const int lrow = lane & 15;
    const int r0   = blockIdx.x * ROWS_PB + wave * 64;

    // ---- build B in LDS (swizzled) + esq, straight from fp32 cb ----
    // slot-within-chunk s = tid; col_l = s>>3, j = s&7, part = (j-col_l)&7.
    // The 8 lanes of a col group hold the 8 parts of one codeword -> esq via
    // 3 xor-shuffles.
    {
        const int col_l = tid >> 3;            // 0..127
        const int jj    = tid & 7;
        const int part  = (jj - col_l) & 7;
        const float* src = cb + col_l * DIM + part * 8;
        char* dst = (char*)sB + tid * 16;
        #pragma unroll
        for (int c = 0; c < 8; ++c) {          // codeword chunk c: cols c*128..
            float4 v0 = *(const float4*)(src + c * 8192);
            float4 v1 = *(const float4*)(src + c * 8192 + 4);
            float es = v0.x * v0.x;
            es = fmaf(v0.y, v0.y, es);
            es = fmaf(v0.z, v0.z, es);
            es = fmaf(v0.w, v0.w, es);
            es = fmaf(v1.x, v1.x, es);
            es = fmaf(v1.y, v1.y, es);
            es = fmaf(v1.z, v1.z, es);
            es = fmaf(v1.w, v1.w, es);
            es += __shfl_xor(es, 1, 64);
            es += __shfl_xor(es, 2, 64);
            es += __shfl_xor(es, 4, 64);
            if (jj == 0) s_esq[c * 128 + col_l] = es;
            uint4 w;
            w.x = f2bfu(-2.f * v0.x) | (f2bfu(-2.f * v0.y) << 16);
            w.y = f2bfu(-2.f * v0.z) | (f2bfu(-2.f * v0.w) << 16);
            w.z = f2bfu(-2.f * v1.x) | (f2bfu(-2.f * v1.y) << 16);
            w.w = f2bfu(-2.f * v1.z) | (f2bfu(-2.f * v1.w) << 16);
            *(uint4*)(dst + c * 16384) = w;
        }
    }

    // ---- A fragments: A[m=lane&15][k=quad*8+j], bf16(z); plus exact fp32
    //      ||z||^2 partials (each lane covers 16 elems of its 4 rows) ----
    bf16x8 a0[4], a1[4];
    float zsq = 0.f;
    #pragma unroll
    for (int t = 0; t < 4; ++t) {
        const float* zr = z + (size_t)(r0 + t * 16 + lrow) * DIM + quad * 8;
        float4 p0 = *(const float4*)(zr);
        float4 p1 = *(const float4*)(zr + 4);
        float4 p2 = *(const float4*)(zr + 32);
        float4 p3 = *(const float4*)(zr + 36);
        zsq = fmaf(p0.x, p0.x, zsq); zsq = fmaf(p0.y, p0.y, zsq);
        zsq = fmaf(p0.z, p0.z, zsq); zsq = fmaf(p0.w, p0.w, zsq);
        zsq = fmaf(p1.x, p1.x, zsq); zsq = fmaf(p1.y, p1.y, zsq);
        zsq = fmaf(p1.z, p1.z, zsq); zsq = fmaf(p1.w, p1.w, zsq);
        zsq = fmaf(p2.x, p2.x, zsq); zsq = fmaf(p2.y, p2.y, zsq);
        zsq = fmaf(p2.z, p2.z, zsq); zsq = fmaf(p2.w, p2.w, zsq);
        zsq = fmaf(p3.x, p3.x, zsq); zsq = fmaf(p3.y, p3.y, zsq);
        zsq = fmaf(p3.z, p3.z, zsq); zsq = fmaf(p3.w, p3.w, zsq);
        a0[t][0] = (short)f2bfu(p0.x); a0[t][1] = (short)f2bfu(p0.y);
        a0[t][2] = (short)f2bfu(p0.z); a0[t][3] = (short)f2bfu(p0.w);
        a0[t][4] = (short)f2bfu(p1.x); a0[t][5] = (short)f2bfu(p1.y);
        a0[t][6] = (short)f2bfu(p1.z); a0[t][7] = (short)f2bfu(p1.w);
        a1[t][0] = (short)f2bfu(p2.x); a1[t][1] = (short)f2bfu(p2.y);
        a1[t][2] = (short)f2bfu(p2.z); a1[t][3] = (short)f2bfu(p2.w);
        a1[t][4] = (short)f2bfu(p3.x); a1[t][5] = (short)f2bfu(p3.y);
        a1[t][6] = (short)f2bfu(p3.z); a1[t][7] = (short)f2bfu(p3.w);
    }

    __syncthreads();   // the ONLY staging barrier

    // ---- barrier-free main loop: 64 groups of 16 codewords ----
    float best[4][4];
    #pragma unroll
    for (int t = 0; t < 4; ++t)
        #pragma unroll
        for (int i = 0; i < 4; ++i) best[t][i] = INFINITY;

    const int pos0 = ((quad + lrow) & 7) * 4;       // b0: part=quad   (K 0..31)
    const int pos1 = ((quad + 4 + lrow) & 7) * 4;   // b1: part=quad+4 (K 32..63)
    const int base = lrow * 32;

    #pragma unroll 2
    for (int ks = 0; ks < 64; ks += 2) {
        const unsigned* bpA = sB + ks * 512 + base;
        const unsigned* bpB = bpA + 512;
        bf16x8 b0A = *(const bf16x8*)(bpA + pos0);
        bf16x8 b1A = *(const bf16x8*)(bpA + pos1);
        bf16x8 b0B = *(const bf16x8*)(bpB + pos0);
        bf16x8 b1B = *(const bf16x8*)(bpB + pos1);
        const float esA = s_esq[ks * 16 + lrow];
        const float esB = s_esq[ks * 16 + 16 + lrow];
        const unsigned cvA = (unsigned)(ks * 16 + lrow);
        const unsigned cvB = cvA + 16u;
        #pragma unroll
        for (int t = 0; t < 4; ++t) {
            f32x4 accA = { esA, esA, esA, esA };   // C col = lane&15 -> ||e||^2
            f32x4 accB = { esB, esB, esB, esB };
            accA = __builtin_amdgcn_mfma_f32_16x16x32_bf16(a0[t], b0A, accA, 0, 0, 0);
            accA = __builtin_amdgcn_mfma_f32_16x16x32_bf16(a1[t], b1A, accA, 0, 0, 0);
            accB = __builtin_amdgcn_mfma_f32_16x16x32_bf16(a0[t], b0B, accB, 0, 0, 0);
            accB = __builtin_amdgcn_mfma_f32_16x16x32_bf16(a1[t], b1B, accB, 0, 0, 0);
            #pragma unroll
            for (int i = 0; i < 4; ++i) {
                unsigned uA = __float_as_uint(accA[i]);
                unsigned uB = __float_as_uint(accB[i]);
                // (u & ~0x3FF) | colv  ->  v_bfi_b32; nested fminf -> v_min3
                float pkA = __uint_as_float((uA & 0xFFFFFC00u) | (cvA & 0x3FFu));
                float pkB = __uint_as_float((uB & 0xFFFFFC00u) | (cvB & 0x3FFu));
                best[t][i] = fminf(best[t][i], fminf(pkA, pkB));
            }
        }
    }

    // ---- min across the 16-lane col group; every lane ends with all 16 mins
    #pragma unroll
    for (int t = 0; t < 4; ++t)
        #pragma unroll
        for (int i = 0; i < 4; ++i) {
            float bs = best[t][i];
            bs = fminf(bs, __shfl_xor(bs, 1, 64));
            bs = fminf(bs, __shfl_xor(bs, 2, 64));
            bs = fminf(bs, __shfl_xor(bs, 4, 64));
            bs = fminf(bs, __shfl_xor(bs, 8, 64));
            best[t][i] = bs;
        }

    // lane's designated (t,i) = (lrow>>2, lrow&3) -> row t*16 + quad*4 + i.
    // Static-index select (rule #20: no runtime indexing into reg arrays).
    float mypk = best[0][0];
    #pragma unroll
    for (int t = 0; t < 4; ++t)
        #pragma unroll
        for (int i = 0; i < 4; ++i)
            if (lrow == t * 4 + i) mypk = best[t][i];

    const unsigned ub = __float_as_uint(mypk);
    s_idx[wave * 64 + (lrow >> 2) * 16 + quad * 4 + (lrow & 3)] = (int)(ub & 0x3FFu);
    // loss contribution: ||z||^2 partial + (||e||^2 - 2<e,z>) of designated row
    float lsum = zsq + __uint_as_float(ub & 0xFFFFFC00u);

    // wave-local LDS exchange: writes above, reads below, same wave only.
    asm volatile("s_waitcnt lgkmcnt(0)" ::: "memory");

    // ---- epilogue: gather exact fp32 codebook rows, coalesced float4 store
    const float4* cb4 = (const float4*)cb;
    float4* out4 = (float4*)out;
    #pragma unroll 4
    for (int g = 0; g < 16; ++g) {
        const int rr = g * 4 + quad;                 // 4 rows per iteration
        const int idx = s_idx[wave * 64 + rr];       // broadcast read
        float4 e = cb4[idx * 16 + lrow];
        out4[(size_t)(r0 + rr) * 16 + lrow] = e;
    }

    // ---- loss reduction: wave -> one atomic per wave ----
    #pragma unroll
    for (int off = 32; off > 0; off >>= 1)
        lsum += __shfl_down(lsum, off, 64);
    if (lane == 0) atomicAdd(ws, lsum);

    __syncthreads();
    if (tid == 0) {
        unsigned old = atomicAdd((unsigned*)ws + 1, 1u);
        if (old == (unsigned)(GRID - 1)) {
            float s = atomicAdd(ws, 0.0f);   // coherent read of final sum
            out[NELEM] = 1.25f * s * (1.0f / (float)NELEM);
        }
    }
}

extern "C" void kernel_launch(void* const* d_in, const int* in_sizes, int n_in,
                              void* d_out, int out_size, void* d_ws, size_t ws_size,
                              hipStream_t stream) {
    const float* z  = (const float*)d_in[0];
    const float* cb = (const float*)d_in[1];
    float* out = (float*)d_out;
    float* ws  = (float*)d_ws;   // [0]=loss accum, [1]=block counter

    hipMemsetAsync(ws, 0, 8, stream);
    vq_fused<<<GRID, 1024, 0, stream>>>(z, cb, out, ws);
}